// Round 5
// baseline (688.398 us; speedup 1.0000x reference)
//
#include <hip/hip_runtime.h>
#include <hip/hip_fp16.h>

#define IMG   512
#define WIN   11
#define TW    64              // tile width  (output cols)
#define TH    32              // tile height (output rows)
#define HR    (TH + WIN - 1)  // 42 h-filtered rows
#define HP2   72              // halfs per hbuf row (64 + 8 pad) -> 144 B, 16B-aligned
#define NT    256

// guarded float4 load of cols c..c+3 from one image row (zero outside)
__device__ __forceinline__ float4 loadg4(const float* __restrict__ rowp,
                                         int c, bool rowok) {
    float4 v = make_float4(0.f, 0.f, 0.f, 0.f);
    if (rowok) {
        if ((unsigned)c <= (unsigned)(IMG - 4)) {
            v = *reinterpret_cast<const float4*>(rowp + c);
        } else {
            if ((unsigned)(c + 0) < IMG) v.x = rowp[c + 0];
            if ((unsigned)(c + 1) < IMG) v.y = rowp[c + 1];
            if ((unsigned)(c + 2) < IMG) v.z = rowp[c + 2];
            if ((unsigned)(c + 3) < IMG) v.w = rowp[c + 3];
        }
    }
    return v;
}

__device__ __forceinline__ float ssim_pt(float mx, float my, float fss, float fxy) {
    const float t   = fmaf(my, my, mx * mx);    // mx^2 + my^2
    const float mxy = mx * my;
    const float sig = fss - t;                  // sxx + syy
    const float sxy = fxy - mxy;
    const float num = fmaf(2.f, mxy, 1e-4f) * fmaf(2.f, sxy, 9e-4f);
    const float den = (t + 1e-4f) * (sig + 9e-4f);
    return num * __builtin_amdgcn_rcpf(den);
}

__device__ __forceinline__ unsigned pk2(float a, float b) {
    union { __half2 h2; unsigned u; } c;
    c.h2 = __floats2half2_rn(a, b);
    return c.u;
}

struct H24 { __half2 h[4]; };   // one 16B LDS read = 8 halfs

// ---------------------------------------------------------------------------
// One block = 64x32 output tile. h-phase: 11-tap horizontal conv of 4 fields
// (x, y, x^2+y^2, x*y) straight from global (float4 register window), results
// packed to f16 in LDS (24.2 KB -> 6 blocks/CU). v-phase: 11-tap vertical conv
// in packed half2 FMA via ds_read_b128, SSIM map in f32, block sum, global
// atomic + counter-based single-kernel finalize.
// ---------------------------------------------------------------------------
__global__ __launch_bounds__(NT, 5)
void ssim_fused(const float* __restrict__ x,
                const float* __restrict__ y,
                const float* __restrict__ kern,
                float* __restrict__ accum,
                int*   __restrict__ counter,
                float* __restrict__ out,
                float invN, int nBlocks)
{
    __shared__ __align__(16) __half hbuf[4][HR][HP2];   // 24,192 B
    __shared__ float wsum[NT / 64];

    const int tid   = threadIdx.x;
    const int bid   = blockIdx.x;
    const int plane = bid >> 7;                 // 128 tiles per plane
    const int rem   = bid & 127;
    const int row0  = (rem >> 3) * TH;          // 16 tile-rows
    const int col0  = (rem & 7)  * TW;          // 8 tile-cols

    const float* __restrict__ xp = x + (size_t)plane * (IMG * IMG);
    const float* __restrict__ yp = y + (size_t)plane * (IMG * IMG);

    // 1D separable weights: w[i] = k2[i][5] / sqrt(k2[5][5])
    float   w[WIN];
    __half2 wh[WIN];
    {
        const float cinv = rsqrtf(kern[5 * WIN + 5]);
        #pragma unroll
        for (int i = 0; i < WIN; ++i) {
            w[i]  = kern[i * WIN + 5] * cinv;
            wh[i] = __float2half2_rn(w[i]);
        }
    }

    // ---- h-phase: 42 rows x 16 quads, 4 outputs/task ----
    for (int task = tid; task < HR * 16; task += NT) {
        const int r  = task >> 4;              // 0..41
        const int q  = task & 15;
        const int gr = row0 - 5 + r;
        const bool rok = (unsigned)gr < IMG;
        const float* xr = xp + (size_t)gr * IMG;
        const float* yr = yp + (size_t)gr * IMG;

        float sx[20], sy[20], ss[20];
        #pragma unroll
        for (int jj = 0; jj < 5; ++jj) {
            const int c = col0 + 4 * q - 8 + 4 * jj;
            const float4 vx = loadg4(xr, c, rok);
            const float4 vy = loadg4(yr, c, rok);
            sx[4*jj+0] = vx.x; sx[4*jj+1] = vx.y; sx[4*jj+2] = vx.z; sx[4*jj+3] = vx.w;
            sy[4*jj+0] = vy.x; sy[4*jj+1] = vy.y; sy[4*jj+2] = vy.z; sy[4*jj+3] = vy.w;
            ss[4*jj+0] = fmaf(vy.x, vy.x, vx.x * vx.x);
            ss[4*jj+1] = fmaf(vy.y, vy.y, vx.y * vx.y);
            ss[4*jj+2] = fmaf(vy.z, vy.z, vx.z * vx.z);
            ss[4*jj+3] = fmaf(vy.w, vy.w, vx.w * vx.w);
        }

        float hx[4]  = {0.f, 0.f, 0.f, 0.f};
        float hy[4]  = {0.f, 0.f, 0.f, 0.f};
        float hs[4]  = {0.f, 0.f, 0.f, 0.f};
        float hxy[4] = {0.f, 0.f, 0.f, 0.f};
        #pragma unroll
        for (int k = 0; k < WIN; ++k) {
            const float wk = w[k];
            #pragma unroll
            for (int j = 0; j < 4; ++j) {
                const int idx = j + k + 3;          // 3..16, compile-time
                hx[j]  = fmaf(wk, sx[idx], hx[j]);
                hy[j]  = fmaf(wk, sy[idx], hy[j]);
                hs[j]  = fmaf(wk, ss[idx], hs[j]);
                hxy[j] = fmaf(wk, sx[idx] * sy[idx], hxy[j]);
            }
        }

        const int hc = 4 * q;                       // half col, 8B-aligned
        *reinterpret_cast<uint2*>(&hbuf[0][r][hc]) = make_uint2(pk2(hx[0],  hx[1]),  pk2(hx[2],  hx[3]));
        *reinterpret_cast<uint2*>(&hbuf[1][r][hc]) = make_uint2(pk2(hy[0],  hy[1]),  pk2(hy[2],  hy[3]));
        *reinterpret_cast<uint2*>(&hbuf[2][r][hc]) = make_uint2(pk2(hs[0],  hs[1]),  pk2(hs[2],  hs[3]));
        *reinterpret_cast<uint2*>(&hbuf[3][r][hc]) = make_uint2(pk2(hxy[0], hxy[1]), pk2(hxy[2], hxy[3]));
    }

    __syncthreads();

    // ---- v-phase: thread -> col-oct o (8 cols), one output row rr ----
    float lsum = 0.f;
    {
        const int o  = tid & 7;                 // oct: cols 8o..8o+7
        const int rr = tid >> 3;                // 0..31 output row
        const __half2 hz = __float2half2_rn(0.f);
        __half2 aX[4], aY[4], aS[4], aP[4];
        #pragma unroll
        for (int e = 0; e < 4; ++e) { aX[e] = hz; aY[e] = hz; aS[e] = hz; aP[e] = hz; }

        #pragma unroll
        for (int t = 0; t < WIN; ++t) {
            const __half2 wk = wh[t];
            const H24 vX = *reinterpret_cast<const H24*>(&hbuf[0][rr + t][8 * o]);
            const H24 vY = *reinterpret_cast<const H24*>(&hbuf[1][rr + t][8 * o]);
            const H24 vS = *reinterpret_cast<const H24*>(&hbuf[2][rr + t][8 * o]);
            const H24 vP = *reinterpret_cast<const H24*>(&hbuf[3][rr + t][8 * o]);
            #pragma unroll
            for (int e = 0; e < 4; ++e) {
                aX[e] = __hfma2(wk, vX.h[e], aX[e]);
                aY[e] = __hfma2(wk, vY.h[e], aY[e]);
                aS[e] = __hfma2(wk, vS.h[e], aS[e]);
                aP[e] = __hfma2(wk, vP.h[e], aP[e]);
            }
        }

        #pragma unroll
        for (int e = 0; e < 4; ++e) {
            const float2 mx = __half22float2(aX[e]);
            const float2 my = __half22float2(aY[e]);
            const float2 fs = __half22float2(aS[e]);
            const float2 fp = __half22float2(aP[e]);
            lsum += ssim_pt(mx.x, my.x, fs.x, fp.x);
            lsum += ssim_pt(mx.y, my.y, fs.y, fp.y);
        }
    }

    // ---- block reduction -> one atomic, counter-based finalize ----
    #pragma unroll
    for (int off = 32; off > 0; off >>= 1)
        lsum += __shfl_down(lsum, off, 64);
    if ((tid & 63) == 0) wsum[tid >> 6] = lsum;
    __syncthreads();
    if (tid == 0) {
        const float s = wsum[0] + wsum[1] + wsum[2] + wsum[3];
        atomicAdd(accum, s);
        __threadfence();
        const int old = atomicAdd(counter, 1);
        if (old == nBlocks - 1) {
            const float tot = atomicAdd(accum, 0.0f);   // coherent read
            out[0] = 1.0f - tot * invN;
        }
    }
}

extern "C" void kernel_launch(void* const* d_in, const int* in_sizes, int n_in,
                              void* d_out, int out_size, void* d_ws, size_t ws_size,
                              hipStream_t stream)
{
    const float* x    = (const float*)d_in[0];
    const float* y    = (const float*)d_in[1];
    const float* kern = (const float*)d_in[2];
    float* out     = (float*)d_out;
    float* accum   = (float*)d_ws;
    int*   counter = (int*)d_ws + 1;

    const int planes  = in_sizes[0] / (IMG * IMG);   // B*C = 64
    const int nBlocks = planes * 128;                // 8192

    hipMemsetAsync(d_ws, 0, 2 * sizeof(float), stream);
    ssim_fused<<<nBlocks, NT, 0, stream>>>(
        x, y, kern, accum, counter, out,
        1.0f / ((float)planes * IMG * IMG), nBlocks);
}